// Round 1
// 270.947 us; speedup vs baseline: 1.0382x; 1.0382x over previous
//
#include <hip/hip_runtime.h>
#include <hip/hip_bf16.h>
#include <cstdint>

using u16 = unsigned short;
using u32 = unsigned int;
using bf16x8 = __attribute__((ext_vector_type(8))) short;
using f32x4  = __attribute__((ext_vector_type(4))) float;

// Problem constants
#define NI 128
#define NC 128
#define RR 36
#define WW 50
#define DD 1024
#define LDC 6400   // = NC*WW
#define ATS 37     // aT row stride (floats), conflict-free
#define IMN ((size_t)NI * RR * DD)   // 4,718,592
#define SN  ((size_t)NC * WW * DD)   // 6,553,600

#define GLL16(g, l) __builtin_amdgcn_global_load_lds(                        \
    (const __attribute__((address_space(1))) void*)(g),                      \
    (__attribute__((address_space(3))) void*)(l), 16, 0, 0)

// constant-address-space float: uniform loads select s_load (SGPR data)
typedef const __attribute__((address_space(4))) float cfloat;

__device__ __forceinline__ float2 bf16pair(u32 u) {
  float2 f;
  f.x = __uint_as_float(u << 16);
  f.y = __uint_as_float(u & 0xffff0000u);
  return f;
}

__device__ __forceinline__ u32 bf16_rne(u32 x) {
  return (x + 0x7FFFu + ((x >> 16) & 1u)) >> 16;
}

// ---------------------------------------------------------------------------
// Kernel 0: convert + embedded dtype sniff (unchanged).
// ---------------------------------------------------------------------------
__global__ __launch_bounds__(256) void convert_in(const void* __restrict__ im_in,
                                                  const void* __restrict__ s_in,
                                                  u16* __restrict__ imB,
                                                  u16* __restrict__ sB,
                                                  int* __restrict__ flag) {
  __shared__ int cnt;
  if (threadIdx.x == 0) cnt = 0;
  __syncthreads();
  const u16* imu = (const u16*)im_in;
  int local = 0;
#pragma unroll
  for (int v = 0; v < 16; ++v) {
    u16 u = imu[threadIdx.x * 16 + v];
    if (((u >> 7) & 0xFF) >= 0xC0) local++;
  }
  if (local) atomicAdd(&cnt, local);
  __syncthreads();
  const int f = (cnt > 4) ? 1 : 0;
  if (blockIdx.x == 0 && threadIdx.x == 0) *flag = f;
  if (!f) return;

  const size_t TOT8 = (IMN + SN) / 8;
  const size_t stride = (size_t)gridDim.x * blockDim.x;
  for (size_t g = (size_t)blockIdx.x * blockDim.x + threadIdx.x; g < TOT8; g += stride) {
    size_t base = g * 8;
    const u32* sp;
    u16* dst;
    if (base < IMN) { sp = (const u32*)im_in + base; dst = imB + base; }
    else            { sp = (const u32*)s_in + (base - IMN); dst = sB + (base - IMN); }
    u16 o[8];
#pragma unroll
    for (int e = 0; e < 8; ++e) o[e] = (u16)bf16_rne(sp[e]);
    *(uint4*)dst = *(const uint4*)o;
  }
}

// ---------------------------------------------------------------------------
// Kernel 1: per-image Gram G[i][r][r'] + caption word norms w1 (unchanged).
// ---------------------------------------------------------------------------
__global__ __launch_bounds__(256) void gram_w1(const u16* __restrict__ im_orig,
                                               const u16* __restrict__ im_conv,
                                               const u16* __restrict__ s_orig,
                                               const u16* __restrict__ s_conv,
                                               const int* __restrict__ flag,
                                               float* __restrict__ G,
                                               float* __restrict__ w1) {
  const u16* im = *flag ? im_conv : im_orig;
  const u16* s  = *flag ? s_conv : s_orig;
  __shared__ u16 ims[48 * 520];        // 49,920 B; reused as float scratch later
  const int b = blockIdx.x;
  const int t = threadIdx.x;
  const int lane = t & 63, wv = t >> 6;
  const int lm = lane & 15, q = lane >> 4;
  f32x4 acc[3][3] = {};

  for (int p = 0; p < 2; ++p) {
    const int kk = p * 512;
#pragma unroll
    for (int v = 0; v < 9; ++v) {
      int u = t + v * 256;          // 0..2303 = 36*64
      int row = u >> 6;
      int kloc = (u & 63) * 8;
      uint4 val = *(const uint4*)(im + (size_t)b * (RR * DD) + (size_t)row * DD + kk + kloc);
      *(uint4*)&ims[row * 520 + kloc] = val;
    }
    if (p == 0) {
#pragma unroll
      for (int v = 0; v < 4; ++v) {
        int u = t + v * 256;
        if (u < 780) {              // 12*520/8 = 780 uint4
          uint4 z; z.x = 0; z.y = 0; z.z = 0; z.w = 0;
          *(uint4*)&ims[36 * 520 + u * 8] = z;
        }
      }
    }
    __syncthreads();
#pragma unroll
    for (int kq = 0; kq < 4; ++kq) {
      const int ks = wv * 4 + kq;
      bf16x8 af[3];
#pragma unroll
      for (int mi = 0; mi < 3; ++mi)
        af[mi] = *(const bf16x8*)&ims[(mi * 16 + lm) * 520 + ks * 32 + q * 8];
#pragma unroll
      for (int mi = 0; mi < 3; ++mi)
#pragma unroll
        for (int ni = 0; ni < 3; ++ni)
          acc[mi][ni] = __builtin_amdgcn_mfma_f32_16x16x32_bf16(af[mi], af[ni], acc[mi][ni], 0, 0, 0);
    }
    __syncthreads();
  }
  float* red = (float*)ims;
  if (wv > 0) {
#pragma unroll
    for (int mi = 0; mi < 3; ++mi)
#pragma unroll
      for (int ni = 0; ni < 3; ++ni)
#pragma unroll
        for (int v = 0; v < 4; ++v) {
          int row = mi * 16 + q * 4 + v;
          int col = ni * 16 + lm;
          red[(wv - 1) * 2304 + row * 48 + col] = acc[mi][ni][v];
        }
  }
  __syncthreads();
  if (wv == 0) {
#pragma unroll
    for (int mi = 0; mi < 3; ++mi)
#pragma unroll
      for (int ni = 0; ni < 3; ++ni)
#pragma unroll
        for (int v = 0; v < 4; ++v) {
          int row = mi * 16 + q * 4 + v;
          int col = ni * 16 + lm;
          float r0 = acc[mi][ni][v] + red[row * 48 + col] +
                     red[2304 + row * 48 + col] + red[4608 + row * 48 + col];
          if (row < RR && col < RR)
            G[(size_t)b * (RR * RR) + row * RR + col] = r0;
        }
  }
  // w1 rows for caption b (no LDS dependency)
  const u16* sc = s + (size_t)b * WW * DD;
  for (int w = wv; w < WW; w += 4) {
    const u16* sp = sc + (size_t)w * DD + lane * 16;
    uint4 A0 = *(const uint4*)sp;
    uint4 A1 = *(const uint4*)(sp + 8);
    float sum = 0.f;
    u32 uu[8] = {A0.x, A0.y, A0.z, A0.w, A1.x, A1.y, A1.z, A1.w};
#pragma unroll
    for (int e = 0; e < 8; ++e) {
      float2 f = bf16pair(uu[e]);
      sum += f.x * f.x + f.y * f.y;
    }
#pragma unroll
    for (int off = 32; off > 0; off >>= 1) sum += __shfl_down(sum, off);
    if (lane == 0) w1[b * WW + w] = sqrtf(sum);
  }
}

// ---------------------------------------------------------------------------
// Kernel 2: raw[ir][cw] = sum_k im[ir][k] * s[cw][k]  (bf16 MFMA, bf16 out)
// M=4608, N=6400, K=1024. NEW: 256x256 tile, 512 thr / 8 waves (2Mx4N,
// 128x64 per wave). K-half (32-wide) ring pipeline: 4 LDS slots per operand
// (256 rows x 32 k = 16 KB each; 128 KB total). Phase H computes K-half H
// (32 MFMA/wave) while staging K-half H+3 into the slot freed by H-1.
// Counted s_waitcnt vmcnt(8) BEFORE each raw s_barrier keeps 2 K-halves
// (8 loads/wave) in flight across every barrier - never drains to 0 in the
// main loop (T3+T4). setprio around the MFMA cluster (T5). Slot layout
// packs 2 rows per 128B line with XOR chunk swizzle: phys 16B-slot
// p = (row&1)*4 + (chunk ^ ((row>>1)&3)) -> ds_read_b128 is 2-way only
// (free). Staging inverts the swizzle on the global source (T2 pattern).
// XCD-bijective block swizzle for 450 wgs (450%8=2 -> m204 variant) (T1).
// ---------------------------------------------------------------------------
#define STAGE(koff, SD)                                                      \
  do {                                                                       \
    GLL16(aP0 + (koff), &ringA[SD][t * 8]);                                  \
    GLL16(aP1 + (koff), &ringA[SD][t * 8 + 4096]);                           \
    GLL16(bP0 + (koff), &ringB[SD][t * 8]);                                  \
    GLL16(bP1 + (koff), &ringB[SD][t * 8 + 4096]);                           \
  } while (0)

#define PHASE(S)                                                             \
  do {                                                                       \
    bf16x8 af[8], bf[4];                                                     \
    _Pragma("unroll")                                                        \
    for (int mi = 0; mi < 8; ++mi)                                           \
      af[mi] = *(const bf16x8*)&ringA[S][aBase + mi * 512];                  \
    _Pragma("unroll")                                                        \
    for (int ni = 0; ni < 4; ++ni)                                           \
      bf[ni] = *(const bf16x8*)&ringB[S][bBase + ni * 512];                  \
    __builtin_amdgcn_s_setprio(1);                                           \
    _Pragma("unroll")                                                        \
    for (int mi = 0; mi < 8; ++mi)                                           \
      _Pragma("unroll")                                                      \
      for (int ni = 0; ni < 4; ++ni)                                         \
        acc[mi][ni] = __builtin_amdgcn_mfma_f32_16x16x32_bf16(               \
            af[mi], bf[ni], acc[mi][ni], 0, 0, 0);                           \
    __builtin_amdgcn_s_setprio(0);                                           \
  } while (0)

#define WAIT_BAR(N)                                                          \
  do {                                                                       \
    asm volatile("s_waitcnt vmcnt(" #N ")" ::: "memory");                    \
    __builtin_amdgcn_s_barrier();                                            \
    asm volatile("" ::: "memory");                                           \
  } while (0)

__global__ __launch_bounds__(512, 2) void gemm_raw(const u16* __restrict__ A_orig,
                                                   const u16* __restrict__ A_conv,
                                                   const u16* __restrict__ B_orig,
                                                   const u16* __restrict__ B_conv,
                                                   const int* __restrict__ flag,
                                                   u16* __restrict__ C) {
  const u16* A = *flag ? A_conv : A_orig;
  const u16* B = *flag ? B_conv : B_orig;
  __shared__ u16 ringA[4][8192];   // 4 slots x 16 KB = 64 KB
  __shared__ u16 ringB[4][8192];   // 64 KB
  const int t = threadIdx.x;

  // T1: XCD-bijective swizzle, nwg=450 (q=56, r=2), then row-major tiles.
  const int orig = blockIdx.x;
  const int xcd = orig & 7, jb = orig >> 3;
  const int wg = (xcd < 2 ? xcd * 57 : 114 + (xcd - 2) * 56) + jb;
  const int tm = wg / 25;
  const int tn = wg - tm * 25;
  const int row0 = tm * 256, col0 = tn * 256;

  const int lane = t & 63, wv = t >> 6;
  const int wm = wv >> 2, wn = wv & 3;          // wave tile: 128 rows x 64 cols
  const int lm = lane & 15, q = lane >> 4;
  // read-side swizzled base (u16 units within a slot); frag mi/ni at +512
  const int chunk = (lm & 1) * 4 + (q ^ ((lm >> 1) & 3));
  const int aBase = (wm * 64 + (lm >> 1)) * 64 + chunk * 8;
  const int bBase = (wn * 32 + (lm >> 1)) * 64 + chunk * 8;

  // staging source pointers: idx -> (row, logical chunk), inverse swizzle
  const int i0 = t, i1 = t + 512;
  const int r0s = (i0 >> 3) * 2 + ((i0 & 7) >> 2);
  const int r1s = (i1 >> 3) * 2 + ((i1 & 7) >> 2);
  const int lc0 = (i0 & 3) ^ ((i0 >> 3) & 3);
  const int lc1 = (i1 & 3) ^ ((i1 >> 3) & 3);
  const u16* aP0 = A + (size_t)(row0 + r0s) * DD + lc0 * 8;
  const u16* aP1 = A + (size_t)(row0 + r1s) * DD + lc1 * 8;
  const u16* bP0 = B + (size_t)(col0 + r0s) * DD + lc0 * 8;
  const u16* bP1 = B + (size_t)(col0 + r1s) * DD + lc1 * 8;

  f32x4 acc[8][4] = {};

  // prologue: stage K-halves 0,1,2 (12 loads/wave); land H0, keep 8 in flight
  STAGE(0, 0);
  STAGE(32, 1);
  STAGE(64, 2);
  WAIT_BAR(8);

  // main loop: phases H = 0..27 (slot = H&3 = j), stage H+3
  for (int k4 = 0; k4 < 7; ++k4) {
    const int kb = k4 * 128 + 96;     // (H+3)*32 base for j=0
#pragma unroll
    for (int j = 0; j < 4; ++j) {
      STAGE(kb + j * 32, ((j + 3) & 3));
      PHASE(j);
      WAIT_BAR(8);
    }
  }
  // epilogue: H = 28..31, vmcnt decays 8 -> 4 -> 0
  STAGE(992, 3);                      // H=28 stages H+3=31 (slot 3)
  PHASE(0);
  WAIT_BAR(8);
  PHASE(1);                           // H=29
  WAIT_BAR(4);
  PHASE(2);                           // H=30
  WAIT_BAR(0);
  PHASE(3);                           // H=31

#pragma unroll
  for (int mi = 0; mi < 8; ++mi)
#pragma unroll
    for (int ni = 0; ni < 4; ++ni)
#pragma unroll
      for (int v = 0; v < 4; ++v) {
        int rr = row0 + wm * 128 + mi * 16 + q * 4 + v;
        int cc = col0 + wn * 64 + ni * 16 + lm;
        C[(size_t)rr * LDC + cc] = (u16)bf16_rne(__float_as_uint(acc[mi][ni][v]));
      }
}

// ---------------------------------------------------------------------------
// Kernel 3: postproc, wave-per-(c,i) pair (unchanged).
// ---------------------------------------------------------------------------
__global__ __launch_bounds__(256, 2) void postproc(const u16* __restrict__ raw,
                                                   const float* __restrict__ G,
                                                   const float* __restrict__ w1,
                                                   const int* __restrict__ s_l,
                                                   float* __restrict__ scores) {
  const int i = blockIdx.y;
  const int wv = threadIdx.x >> 6;
  const int c = blockIdx.x * 4 + wv;
  const int lane = threadIdx.x & 63;
  __shared__ float aT[4][WW * ATS];         // 4 * 7400 B
  __shared__ float nrm9_s[4][RR];           // 576 B
  const int L = s_l[c];

  // ---- phase 1: lanes = regions ----
  if (lane < RR) {
    const u16* rp = raw + (size_t)(i * RR + lane) * LDC + c * WW;
    float sum = 0.f;
#pragma unroll
    for (int j = 0; j < 25; ++j) {
      float2 v = bf16pair(((const u32*)rp)[j]);
      float x0 = v.x > 0.f ? v.x : 0.1f * v.x;
      float x1 = v.y > 0.f ? v.y : 0.1f * v.y;
      if (2 * j     >= L) x0 = 0.f;
      if (2 * j + 1 >= L) x1 = 0.f;
      aT[wv][(2 * j) * ATS + lane]     = x0;
      aT[wv][(2 * j + 1) * ATS + lane] = x1;
      sum += x0 * x0 + x1 * x1;
    }
    nrm9_s[wv][lane] = 9.0f / (sqrtf(sum) + 1e-8f);
  }
  __syncthreads();

  // ---- phases 2-4: uniform flow, lanes = words (clamped) ----
  const int wIdx = lane < WW ? lane : WW - 1;
  const float* row = &aT[wv][wIdx * ATS];
  cfloat* Gp = (cfloat*)(G + (size_t)i * (RR * RR));

  float x[RR];
  float m = -1e30f;
#pragma unroll
  for (int r = 0; r < RR; ++r) {
    x[r] = row[r];
    m = fmaxf(m, x[r] * nrm9_s[wv][r]);
  }
  float e[RR];
  float sum = 0.f, w12r = 0.f;
#pragma unroll
  for (int r = 0; r < RR; ++r) {
    float er = __expf(x[r] * nrm9_s[wv][r] - m);
    e[r] = er;
    sum += er;
    w12r += er * (x[r] > 0.f ? x[r] : 10.0f * x[r]);   // inverse-leaky: raw value
  }
  float qq2 = 0.f;
#pragma unroll
  for (int r = 0; r < RR; ++r) {
    float h = 0.5f * Gp[r * RR + r] * e[r];
#pragma unroll
    for (int j = r + 1; j < RR; ++j)
      h += Gp[r * RR + j] * e[j];
    qq2 += e[r] * h;
  }
  float qq = 2.0f * qq2;
  float w1v = w1[c * WW + wIdx];
  float denom = fmaxf(w1v * sqrtf(fmaxf(qq, 0.f)), 1e-8f * sum);
  float rs = w12r / denom;
  float ew = (lane < L) ? __expf(6.0f * rs) : 0.f;
#pragma unroll
  for (int off = 32; off > 0; off >>= 1) ew += __shfl_down(ew, off);
  if (lane == 0) scores[i * NC + c] = logf(ew) * (1.0f / 6.0f);
}

// ---------------------------------------------------------------------------
// Kernel 4: hardest-negative contrastive loss over scores (128x128).
// ---------------------------------------------------------------------------
__global__ __launch_bounds__(128) void loss_k(const float* __restrict__ scores,
                                              u32* __restrict__ out) {
  __shared__ float diag[NI];
  __shared__ float red[NI];
  const int t = threadIdx.x;
  diag[t] = scores[t * NC + t];
  __syncthreads();
  const float di = diag[t];
  float rowmax = 0.f, colmax = 0.f;
  for (int k = 0; k < NC; ++k) {
    if (k != t) {
      float sr = scores[t * NC + k];
      rowmax = fmaxf(rowmax, fmaxf(0.2f + sr - di, 0.f));
      float sc = scores[k * NC + t];
      colmax = fmaxf(colmax, fmaxf(0.2f + sc - di, 0.f));
    }
  }
  red[t] = rowmax + colmax;
  __syncthreads();
  for (int st = 64; st > 0; st >>= 1) {
    if (t < st) red[t] += red[t + st];
    __syncthreads();
  }
  if (t == 0) {
    u32 b = bf16_rne(__float_as_uint(red[0]));
    out[0] = b | (b << 16);
  }
}

// ---------------------------------------------------------------------------
extern "C" void kernel_launch(void* const* d_in, const int* in_sizes, int n_in,
                              void* d_out, int out_size, void* d_ws, size_t ws_size,
                              hipStream_t stream) {
  const void* im_in = d_in[0];
  const void* s_in  = d_in[1];
  const int*  sl    = (const int*)d_in[2];

  char* ws = (char*)d_ws;
  u16*   imB    = (u16*)ws;                                  //  9,437,184 B
  u16*   sB     = (u16*)(ws + 9437184);                      // 13,107,200 B
  u16*   raw    = (u16*)(ws + 22544384);                     // 58,982,400 B (bf16)
  float* G      = (float*)(ws + 22544384 + 58982400);        //    663,552 B
  float* w1     = G + 128 * RR * RR;                         //     25,600 B
  float* scores = w1 + NC * WW;                              //     65,536 B
  int*   flag   = (int*)(scores + NI * NC);

  convert_in<<<dim3(2048), dim3(256), 0, stream>>>(im_in, s_in, imB, sB, flag);
  gram_w1<<<dim3(128), dim3(256), 0, stream>>>((const u16*)im_in, imB,
                                               (const u16*)s_in, sB, flag, G, w1);
  gemm_raw<<<dim3(450), dim3(512), 0, stream>>>((const u16*)im_in, imB,
                                                (const u16*)s_in, sB, flag, raw);
  postproc<<<dim3(32, 128), dim3(256), 0, stream>>>(raw, G, w1, sl, scores);
  loss_k<<<dim3(1), dim3(128), 0, stream>>>(scores, (u32*)d_out);
}